// Round 12
// baseline (208.013 us; speedup 1.0000x reference)
//
#include <hip/hip_runtime.h>
#include <math.h>

#define D 256
#define H 512
#define TT 10
#define THRESH 0.4f
#define KS 8          // K steps of 32 (D = 256)
#define NSPLIT 8      // scan blocks per graph

typedef __attribute__((ext_vector_type(8))) _Float16 half8;
typedef __attribute__((ext_vector_type(4))) float f32x4;

// ---------------------------------------------------------------------------
// K0: swizzle W1 [D][H] f32 -> fp16 MFMA B-fragments in ws (256 KB).
// layout (half8 = 16B units): idx = (n*8 + k)*64 + lane
//   element i = W1[k*32 + (lane>>4)*8 + i][n*16 + (lane&15)]
// n-tile n = contiguous 8 KB; half-tile (n,kk) = 4 KB at n*8192 + kk*4096.
// ---------------------------------------------------------------------------
__global__ __launch_bounds__(256) void w1_prep(const float* __restrict__ W1,
                                               short* __restrict__ W1s)
{
    const int tid = blockIdx.x * 256 + threadIdx.x;   // 16384 threads
    const int lane = tid & 63;
    const int cell = tid >> 6;                        // 0..255 = (n,k)
    const int k = cell & 7;
    const int n = cell >> 3;
    const int row0 = k * 32 + (lane >> 4) * 8;
    const int col = n * 16 + (lane & 15);
    _Float16 h8[8];
    #pragma unroll
    for (int i = 0; i < 8; ++i)
        h8[i] = (_Float16)W1[(size_t)(row0 + i) * H + col];   // RTN
    *reinterpret_cast<half8*>(W1s + (((size_t)n * 8 + k) * 64 + lane) * 8) =
        *reinterpret_cast<half8*>(h8);
}

// ---------------------------------------------------------------------------
// K1: gate MLP, fp16 1-term MFMA. 2D wave split: 4 waves/block =
// 2 row-groups x 2 H-halves; each wave: 32 rows x 16 n-tiles (H/2).
// 4096 waves total = 4 waves/SIMD (TLP). Per-wave private 2 x 4 KB LDS
// double buffer (half-n-tile stages: 4 loads, vmcnt(4)), free-running,
// n-tile rotation desyncs SIMD-mates. One final barrier combines halves.
// LDS 36.5 KB -> 4 blocks/CU = 16 waves/CU; VGPR ~110 (<=128 for 4/SIMD).
// ---------------------------------------------------------------------------
__global__ __launch_bounds__(256, 4) void gate_mfma(
    const float* __restrict__ h_sub,
    const short* __restrict__ W1s,
    const float* __restrict__ b1,
    const float* __restrict__ W2,
    const float* __restrict__ b2,
    float* __restrict__ submask,
    unsigned* __restrict__ gbits)      // [S/32]
{
    __shared__ __align__(16) short sW[4][2][2048];   // per-wave 2 x 4 KB
    __shared__ float sb1[H], sw2[H];
    __shared__ float red[2][2][32];    // [rgroup][half][row in 32]
    const int tid = threadIdx.x;
    const int lane = tid & 63;
    const int w = tid >> 6;            // wave id 0..3
    const int half = w & 1;            // H-half
    const int r = w >> 1;              // row-group
    const int base = blockIdx.x * 64 + r * 32;
    const int rotn = (blockIdx.x + 5 * w) & 15;      // n-tile rotation
    const float bb = b2[0];

    // stage b1 / W2 into LDS (visible after the one barrier)
    {
        int i = tid * 2;
        *reinterpret_cast<float2*>(&sb1[i]) = *reinterpret_cast<const float2*>(&b1[i]);
        *reinterpret_cast<float2*>(&sw2[i]) = *reinterpret_cast<const float2*>(&W2[i]);
    }

    // A fragments fp16: 2 s-tiles x 8 k = 64 VGPR
    half8 af[2][KS];
    #pragma unroll
    for (int s = 0; s < 2; ++s) {
        const int row = base + s * 16 + (lane & 15);
        const float* rp = h_sub + (size_t)row * D + (lane >> 4) * 8;
        #pragma unroll
        for (int k = 0; k < KS; ++k) {
            float x[8];
            *reinterpret_cast<float4*>(&x[0]) =
                *reinterpret_cast<const float4*>(rp + k * 32);
            *reinterpret_cast<float4*>(&x[4]) =
                *reinterpret_cast<const float4*>(rp + k * 32 + 4);
            _Float16 h8[8];
            #pragma unroll
            for (int i = 0; i < 8; ++i) h8[i] = (_Float16)x[i];
            af[s][k] = *reinterpret_cast<half8*>(h8);
        }
    }

    // one barrier: sb1/sw2 visible AND all prologue vmem drained
    // (hipcc emits s_waitcnt vmcnt(0) before s_barrier) -> clean vmcnt.
    __syncthreads();

    // n-tile for stage index j (0..15) of this wave's half
    auto ntile = [&](int j) { return half * 16 + ((j + rotn) & 15); };
    // stage s (0..31): half-n-tile (j = s>>1, kk = s&1), 4 KB, 4 loads
    auto stage = [&](int s, int b) {
        const int n = ntile(s >> 1), kk = s & 1;
        const char* gp = (const char*)W1s + (size_t)n * 8192 + (size_t)kk * 4096
                       + (size_t)lane * 16;
        char* lp0 = (char*)&sW[w][b][0] + lane * 16;
        #pragma unroll
        for (int i = 0; i < 4; ++i) {
            __builtin_amdgcn_global_load_lds(
                (const __attribute__((address_space(1))) void*)(gp + i * 1024),
                (__attribute__((address_space(3))) void*)(lp0 + i * 1024),
                16, 0, 0);
        }
    };

    stage(0, 0);
    stage(1, 1);

    float lp[2][4] = {{0.f,0.f,0.f,0.f},{0.f,0.f,0.f,0.f}};
    f32x4 acc[2];

    for (int s = 0; s < 32; ++s) {
        // stage s landed; stage s+1's 4 loads stay in flight
        if (s < 31) asm volatile("s_waitcnt vmcnt(4)" ::: "memory");
        else        asm volatile("s_waitcnt vmcnt(0)" ::: "memory");
        __builtin_amdgcn_sched_barrier(0);

        const int kk = s & 1;
        if (kk == 0) {
            acc[0] = (f32x4){0.f,0.f,0.f,0.f};
            acc[1] = (f32x4){0.f,0.f,0.f,0.f};
        }
        const short* buf = &sW[w][s & 1][0];
        #pragma unroll
        for (int k = 0; k < 4; ++k) {
            half8 bh = *reinterpret_cast<const half8*>(buf + (k * 64 + lane) * 8);
            acc[0] = __builtin_amdgcn_mfma_f32_16x16x32_f16(af[0][kk * 4 + k], bh, acc[0], 0, 0, 0);
            acc[1] = __builtin_amdgcn_mfma_f32_16x16x32_f16(af[1][kk * 4 + k], bh, acc[1], 0, 0, 0);
        }
        if (kk == 1) {
            // epilogue for the finished n-tile's 16 hidden cols
            const int hc = ntile(s >> 1) * 16 + (lane & 15);
            const float b1h = sb1[hc], w2h = sw2[hc];
            #pragma unroll
            for (int t = 0; t < 2; ++t)
                #pragma unroll
                for (int j = 0; j < 4; ++j) {
                    float v = acc[t][j] + b1h;
                    v = v > 0.f ? v : 0.f;
                    lp[t][j] = fmaf(v, w2h, lp[t][j]);
                }
        }

        __builtin_amdgcn_sched_barrier(0);
        if (s < 30) stage(s + 2, s & 1);   // refill finished buf
    }

    // butterfly over the 16 h-cols (low 4 lane bits)
    #pragma unroll
    for (int m = 1; m < 16; m <<= 1)
        #pragma unroll
        for (int t = 0; t < 2; ++t)
            #pragma unroll
            for (int j = 0; j < 4; ++j)
                lp[t][j] += __shfl_xor(lp[t][j], m);

    // write this wave's 32-row half-partials: row = t*16 + g*4 + j
    if ((lane & 15) == 0) {
        const int g = lane >> 4;
        #pragma unroll
        for (int t = 0; t < 2; ++t)
            #pragma unroll
            for (int j = 0; j < 4; ++j)
                red[r][half][t * 16 + g * 4 + j] = lp[t][j];
    }
    __syncthreads();

    // combine halves: waves with half==0 finalize their 32 rows
    if (half == 0) {
        const bool act = lane < 32;
        float sig = 0.f;
        if (act) {
            float logit = red[r][0][lane] + red[r][1][lane] + bb;
            sig = 1.f / (1.f + expf(-logit));
        }
        unsigned long long bal = __ballot(act && (sig > THRESH));
        if (act) submask[base + lane] = sig;
        if (lane == 0) gbits[blockIdx.x * 2 + r] = (unsigned)bal;
    }
}

// ---------------------------------------------------------------------------
// K2a: mask scan, NSPLIT blocks per graph -> partial sums/counts in ws
// ---------------------------------------------------------------------------
__global__ __launch_bounds__(256) void seg_scan(
    const float* __restrict__ h_sub,    // [S][D]
    const int*   __restrict__ mask,     // [B][S]
    const unsigned* __restrict__ gbits, // [S/32]
    float* __restrict__ psum,           // [B*NSPLIT][D]
    int*   __restrict__ pcnt,           // [B*NSPLIT]
    int S)
{
    const int i = blockIdx.x / NSPLIT;
    const int p = blockIdx.x % NSPLIT;
    const int tid = threadIdx.x;
    const int lane = tid & 63;
    const int w = tid >> 6;
    const int seg = S / NSPLIT;                 // 8192
    const int start = p * seg;
    const int* mrow = mask + (size_t)i * S + start;

    __shared__ unsigned sbits[8192 / 32];       // 256 words = 1 KB
    {
        const int nw = seg / 32;
        for (int t = tid; t < nw; t += 256) sbits[t] = gbits[(start >> 5) + t];
    }
    __syncthreads();

    float4 acc = make_float4(0.f, 0.f, 0.f, 0.f);
    int cnt = 0;

    const int per = seg / 4;                    // per wave: 2048
    for (int base = w * per; base < (w + 1) * per; base += 256) {
        const int j0 = base + (lane << 2);
        int4 m4 = *reinterpret_cast<const int4*>(mrow + j0);
        const unsigned bw = sbits[j0 >> 5];
        const int sh = j0 & 31;
        unsigned long long bal[4];
        bal[0] = __ballot((m4.x != 0) & ((bw >> (sh + 0)) & 1u));
        bal[1] = __ballot((m4.y != 0) & ((bw >> (sh + 1)) & 1u));
        bal[2] = __ballot((m4.z != 0) & ((bw >> (sh + 2)) & 1u));
        bal[3] = __ballot((m4.w != 0) & ((bw >> (sh + 3)) & 1u));
        #pragma unroll
        for (int s = 0; s < 4; ++s) {
            unsigned long long b = bal[s];
            while (b) {
                int t = __builtin_ctzll(b);
                b &= b - 1;
                int jj = start + base + (t << 2) + s;
                float4 hv = *reinterpret_cast<const float4*>(
                    h_sub + (size_t)jj * D + (lane << 2));
                acc.x += hv.x; acc.y += hv.y; acc.z += hv.z; acc.w += hv.w;
                cnt++;
            }
        }
    }

    __shared__ float ssum[4][D];
    __shared__ int   scnt[4];
    *reinterpret_cast<float4*>(&ssum[w][lane << 2]) = acc;
    if (lane == 0) scnt[w] = cnt;
    __syncthreads();

    float a = ssum[0][tid] + ssum[1][tid] + ssum[2][tid] + ssum[3][tid];
    psum[(size_t)blockIdx.x * D + tid] = a;
    if (tid == 0) pcnt[blockIdx.x] = scnt[0] + scnt[1] + scnt[2] + scnt[3];
}

// ---------------------------------------------------------------------------
// K2b: combine partials -> mean, cosine, classifier logits
// ---------------------------------------------------------------------------
__global__ __launch_bounds__(256) void seg_combine(
    const float* __restrict__ h_graph,  // [B][D]
    const float* __restrict__ psum,     // [B*NSPLIT][D]
    const int*   __restrict__ pcnt,     // [B*NSPLIT]
    const float* __restrict__ Wc,       // [2D][TT]
    const float* __restrict__ bc,       // [TT]
    float* __restrict__ logits,         // [B][TT]
    float* __restrict__ cos_ws)         // [B]
{
    const int i = blockIdx.x;
    const int tid = threadIdx.x;
    const int lane = tid & 63;
    const int w = tid >> 6;

    float a = 0.f;
    int c = 0;
    #pragma unroll
    for (int p = 0; p < NSPLIT; ++p) {
        a += psum[((size_t)i * NSPLIT + p) * D + tid];
        c += pcnt[i * NSPLIT + p];
    }
    a = (c > 0) ? (a / (float)c) : 0.f;
    const float g = h_graph[(size_t)i * D + tid];

    float r0 = a * a, r1 = g * g, r2 = a * g;
    #pragma unroll
    for (int m = 1; m < 64; m <<= 1) {
        r0 += __shfl_xor(r0, m);
        r1 += __shfl_xor(r1, m);
        r2 += __shfl_xor(r2, m);
    }
    __shared__ float red[4][3];
    if (lane == 0) { red[w][0] = r0; red[w][1] = r1; red[w][2] = r2; }
    __syncthreads();
    if (tid == 0) {
        float a2 = red[0][0] + red[1][0] + red[2][0] + red[3][0];
        float g2 = red[0][1] + red[1][1] + red[2][1] + red[3][1];
        float ag = red[0][2] + red[1][2] + red[2][2] + red[3][2];
        float an = sqrtf(a2), gn = sqrtf(g2);
        float cs = (c > 0) ? (ag / (fmaxf(an, 1e-12f) * fmaxf(gn, 1e-12f))) : 0.f;
        cos_ws[i] = cs;
    }

    float lg[TT];
    #pragma unroll
    for (int t = 0; t < TT; ++t)
        lg[t] = g * Wc[(size_t)tid * TT + t] + a * Wc[(size_t)(D + tid) * TT + t];
    #pragma unroll
    for (int m = 1; m < 64; m <<= 1)
        #pragma unroll
        for (int t = 0; t < TT; ++t) lg[t] += __shfl_xor(lg[t], m);
    __shared__ float lpart[4][TT];
    if (lane == 0)
        #pragma unroll
        for (int t = 0; t < TT; ++t) lpart[w][t] = lg[t];
    __syncthreads();
    if (tid < TT)
        logits[(size_t)i * TT + tid] =
            lpart[0][tid] + lpart[1][tid] + lpart[2][tid] + lpart[3][tid] + bc[tid];
}

// ---------------------------------------------------------------------------
__global__ void loss_kernel(const float* __restrict__ cos_ws,
                            float* __restrict__ out, int B)
{
    const int lane = threadIdx.x;
    float s = 0.f;
    for (int i = lane; i < B; i += 64) s += cos_ws[i];
    #pragma unroll
    for (int m = 1; m < 64; m <<= 1) s += __shfl_xor(s, m);
    if (lane == 0) out[0] = 1.0f - s / (float)B;
}

// ---------------------------------------------------------------------------
extern "C" void kernel_launch(void* const* d_in, const int* in_sizes, int n_in,
                              void* d_out, int out_size, void* d_ws, size_t ws_size,
                              hipStream_t stream)
{
    const float* h_graph = (const float*)d_in[0];
    const float* h_sub   = (const float*)d_in[1];
    const float* W1      = (const float*)d_in[2];
    const float* b1      = (const float*)d_in[3];
    const float* W2      = (const float*)d_in[4];
    const float* b2      = (const float*)d_in[5];
    const float* Wc      = (const float*)d_in[6];
    const float* bc      = (const float*)d_in[7];
    const int*   mask    = (const int*)d_in[8];

    const int B = in_sizes[0] / D;
    const int S = in_sizes[1] / D;

    float* out     = (float*)d_out;
    float* logits  = out;                       // [B*TT]
    float* loss    = out + (size_t)B * TT;      // [1]
    float* submask = loss + 1;                  // [S]

    char* ws = (char*)d_ws;
    short*    W1s    = (short*)ws;                       // 256 KB fp16 frags
    unsigned* gbits  = (unsigned*)(ws + 512 * 1024);     // 8 KB
    int*      pcnt   = (int*)(ws + 528 * 1024);          // 16 KB
    float*    cos_ws = (float*)(ws + 560 * 1024);        // 2 KB
    float*    psum   = (float*)(ws + 1024 * 1024);       // 4 MB

    w1_prep<<<64, 256, 0, stream>>>(W1, W1s);
    gate_mfma<<<S / 64, 256, 0, stream>>>(h_sub, W1s, b1, W2, b2, submask, gbits);
    seg_scan<<<B * NSPLIT, 256, 0, stream>>>(h_sub, mask, gbits, psum, pcnt, S);
    seg_combine<<<B, 256, 0, stream>>>(h_graph, psum, pcnt, Wc, bc, logits, cos_ws);
    loss_kernel<<<1, 64, 0, stream>>>(cos_ws, loss, B);
}

// Round 13
// 80.542 us; speedup vs baseline: 2.5827x; 2.5827x over previous
//
#include <hip/hip_runtime.h>
#include <math.h>

#define D 256
#define H 512
#define TT 10
#define THRESH 0.4f
#define KS 8          // K steps of 32 (D = 256)
#define NSPLIT 8      // scan blocks per graph

typedef __attribute__((ext_vector_type(8))) _Float16 half8;
typedef __attribute__((ext_vector_type(4))) float f32x4;

// ---------------------------------------------------------------------------
// K0: swizzle W1 [D][H] f32 -> fp16 MFMA B-fragments in ws (256 KB).
// layout (half8 = 16B units): idx = (n*8 + k)*64 + lane
//   element i = W1[k*32 + (lane>>4)*8 + i][n*16 + (lane&15)]
// n-tile n = contiguous 8 KB; half-tile (n,kk) = 4 KB at n*8192 + kk*4096.
// ---------------------------------------------------------------------------
__global__ __launch_bounds__(256) void w1_prep(const float* __restrict__ W1,
                                               short* __restrict__ W1s)
{
    const int tid = blockIdx.x * 256 + threadIdx.x;   // 16384 threads
    const int lane = tid & 63;
    const int cell = tid >> 6;                        // 0..255 = (n,k)
    const int k = cell & 7;
    const int n = cell >> 3;
    const int row0 = k * 32 + (lane >> 4) * 8;
    const int col = n * 16 + (lane & 15);
    _Float16 h8[8];
    #pragma unroll
    for (int i = 0; i < 8; ++i)
        h8[i] = (_Float16)W1[(size_t)(row0 + i) * H + col];   // RTN
    *reinterpret_cast<half8*>(W1s + (((size_t)n * 8 + k) * 64 + lane) * 8) =
        *reinterpret_cast<half8*>(h8);
}

// ---------------------------------------------------------------------------
// K1: gate MLP, fp16 1-term MFMA. 2D wave split: 4 waves/block =
// 2 row-groups x 2 H-halves; each wave: 32 rows x 16 n-tiles (H/2).
// 4096 waves = 4 waves/SIMD. Per-wave private 2 x 4 KB LDS double buffer.
// STATIC af INDEXING (rule #20 fix vs round 12): the n-tile loop handles
// both 4 KB halves explicitly — kk=0 uses af[t][0..3], kk=1 af[t][4..7],
// all compile-time. No scratch.
// LDS 36.5 KB -> 4 blocks/CU = 16 waves/CU; VGPR ~110.
// ---------------------------------------------------------------------------
__global__ __launch_bounds__(256, 4) void gate_mfma(
    const float* __restrict__ h_sub,
    const short* __restrict__ W1s,
    const float* __restrict__ b1,
    const float* __restrict__ W2,
    const float* __restrict__ b2,
    float* __restrict__ submask,
    unsigned* __restrict__ gbits)      // [S/32]
{
    __shared__ __align__(16) short sW[4][2][2048];   // per-wave 2 x 4 KB
    __shared__ float sb1[H], sw2[H];
    __shared__ float red[2][2][32];    // [rgroup][half][row in 32]
    const int tid = threadIdx.x;
    const int lane = tid & 63;
    const int w = tid >> 6;            // wave id 0..3
    const int half = w & 1;            // H-half
    const int r = w >> 1;              // row-group
    const int base = blockIdx.x * 64 + r * 32;
    const int rotn = (blockIdx.x + 5 * w) & 15;      // n-tile rotation
    const float bb = b2[0];

    // stage b1 / W2 into LDS (visible after the one barrier)
    {
        int i = tid * 2;
        *reinterpret_cast<float2*>(&sb1[i]) = *reinterpret_cast<const float2*>(&b1[i]);
        *reinterpret_cast<float2*>(&sw2[i]) = *reinterpret_cast<const float2*>(&W2[i]);
    }

    // A fragments fp16: 2 s-tiles x 8 k = 64 VGPR (all static indexing)
    half8 af[2][KS];
    #pragma unroll
    for (int s = 0; s < 2; ++s) {
        const int row = base + s * 16 + (lane & 15);
        const float* rp = h_sub + (size_t)row * D + (lane >> 4) * 8;
        #pragma unroll
        for (int k = 0; k < KS; ++k) {
            float x[8];
            *reinterpret_cast<float4*>(&x[0]) =
                *reinterpret_cast<const float4*>(rp + k * 32);
            *reinterpret_cast<float4*>(&x[4]) =
                *reinterpret_cast<const float4*>(rp + k * 32 + 4);
            _Float16 h8[8];
            #pragma unroll
            for (int i = 0; i < 8; ++i) h8[i] = (_Float16)x[i];
            af[s][k] = *reinterpret_cast<half8*>(h8);
        }
    }

    // one barrier: sb1/sw2 visible AND all prologue vmem drained
    // (hipcc emits s_waitcnt vmcnt(0) before s_barrier) -> clean vmcnt.
    __syncthreads();

    // n-tile for iteration j (0..15) of this wave's half
    auto ntile = [&](int j) { return half * 16 + ((j + rotn) & 15); };
    // stage half kk of n-tile index j into buffer b: 4 KB, 4 loads
    auto stage = [&](int j, int kk, int b) {
        const char* gp = (const char*)W1s + (size_t)ntile(j) * 8192
                       + (size_t)kk * 4096 + (size_t)lane * 16;
        char* lp0 = (char*)&sW[w][b][0] + lane * 16;
        #pragma unroll
        for (int i = 0; i < 4; ++i) {
            __builtin_amdgcn_global_load_lds(
                (const __attribute__((address_space(1))) void*)(gp + i * 1024),
                (__attribute__((address_space(3))) void*)(lp0 + i * 1024),
                16, 0, 0);
        }
    };

    stage(0, 0, 0);
    stage(0, 1, 1);

    float lp[2][4] = {{0.f,0.f,0.f,0.f},{0.f,0.f,0.f,0.f}};

    for (int j = 0; j < 16; ++j) {
        f32x4 acc0 = (f32x4){0.f,0.f,0.f,0.f};
        f32x4 acc1 = (f32x4){0.f,0.f,0.f,0.f};

        // ---- half kk=0 (buf0): af[t][0..3], all static ----
        asm volatile("s_waitcnt vmcnt(4)" ::: "memory");   // buf0 landed
        __builtin_amdgcn_sched_barrier(0);
        {
            const short* buf = &sW[w][0][0];
            #pragma unroll
            for (int k = 0; k < 4; ++k) {
                half8 bh = *reinterpret_cast<const half8*>(buf + (k * 64 + lane) * 8);
                acc0 = __builtin_amdgcn_mfma_f32_16x16x32_f16(af[0][k], bh, acc0, 0, 0, 0);
                acc1 = __builtin_amdgcn_mfma_f32_16x16x32_f16(af[1][k], bh, acc1, 0, 0, 0);
            }
        }
        __builtin_amdgcn_sched_barrier(0);
        if (j < 15) stage(j + 1, 0, 0);                    // refill buf0

        // ---- half kk=1 (buf1): af[t][4..7], all static ----
        if (j < 15) asm volatile("s_waitcnt vmcnt(4)" ::: "memory");
        else        asm volatile("s_waitcnt vmcnt(0)" ::: "memory");
        __builtin_amdgcn_sched_barrier(0);
        {
            const short* buf = &sW[w][1][0];
            #pragma unroll
            for (int k = 0; k < 4; ++k) {
                half8 bh = *reinterpret_cast<const half8*>(buf + (k * 64 + lane) * 8);
                acc0 = __builtin_amdgcn_mfma_f32_16x16x32_f16(af[0][4 + k], bh, acc0, 0, 0, 0);
                acc1 = __builtin_amdgcn_mfma_f32_16x16x32_f16(af[1][4 + k], bh, acc1, 0, 0, 0);
            }
        }

        // epilogue for this n-tile's 16 hidden cols: +b1, relu, dot W2
        {
            const int hc = ntile(j) * 16 + (lane & 15);
            const float b1h = sb1[hc], w2h = sw2[hc];
            #pragma unroll
            for (int jj = 0; jj < 4; ++jj) {
                float v0 = acc0[jj] + b1h;
                v0 = v0 > 0.f ? v0 : 0.f;
                lp[0][jj] = fmaf(v0, w2h, lp[0][jj]);
                float v1 = acc1[jj] + b1h;
                v1 = v1 > 0.f ? v1 : 0.f;
                lp[1][jj] = fmaf(v1, w2h, lp[1][jj]);
            }
        }
        __builtin_amdgcn_sched_barrier(0);
        if (j < 15) stage(j + 1, 1, 1);                    // refill buf1
    }

    // butterfly over the 16 h-cols (low 4 lane bits)
    #pragma unroll
    for (int m = 1; m < 16; m <<= 1)
        #pragma unroll
        for (int t = 0; t < 2; ++t)
            #pragma unroll
            for (int j = 0; j < 4; ++j)
                lp[t][j] += __shfl_xor(lp[t][j], m);

    // write this wave's 32-row half-partials: row = t*16 + g*4 + j
    if ((lane & 15) == 0) {
        const int g = lane >> 4;
        #pragma unroll
        for (int t = 0; t < 2; ++t)
            #pragma unroll
            for (int j = 0; j < 4; ++j)
                red[r][half][t * 16 + g * 4 + j] = lp[t][j];
    }
    __syncthreads();

    // combine halves: waves with half==0 finalize their 32 rows
    if (half == 0) {
        const bool act = lane < 32;
        float sig = 0.f;
        if (act) {
            float logit = red[r][0][lane] + red[r][1][lane] + bb;
            sig = 1.f / (1.f + expf(-logit));
        }
        unsigned long long bal = __ballot(act && (sig > THRESH));
        if (act) submask[base + lane] = sig;
        if (lane == 0) gbits[blockIdx.x * 2 + r] = (unsigned)bal;
    }
}

// ---------------------------------------------------------------------------
// K2a: mask scan, NSPLIT blocks per graph -> partial sums/counts in ws
// ---------------------------------------------------------------------------
__global__ __launch_bounds__(256) void seg_scan(
    const float* __restrict__ h_sub,    // [S][D]
    const int*   __restrict__ mask,     // [B][S]
    const unsigned* __restrict__ gbits, // [S/32]
    float* __restrict__ psum,           // [B*NSPLIT][D]
    int*   __restrict__ pcnt,           // [B*NSPLIT]
    int S)
{
    const int i = blockIdx.x / NSPLIT;
    const int p = blockIdx.x % NSPLIT;
    const int tid = threadIdx.x;
    const int lane = tid & 63;
    const int w = tid >> 6;
    const int seg = S / NSPLIT;                 // 8192
    const int start = p * seg;
    const int* mrow = mask + (size_t)i * S + start;

    __shared__ unsigned sbits[8192 / 32];       // 256 words = 1 KB
    {
        const int nw = seg / 32;
        for (int t = tid; t < nw; t += 256) sbits[t] = gbits[(start >> 5) + t];
    }
    __syncthreads();

    float4 acc = make_float4(0.f, 0.f, 0.f, 0.f);
    int cnt = 0;

    const int per = seg / 4;                    // per wave: 2048
    for (int base = w * per; base < (w + 1) * per; base += 256) {
        const int j0 = base + (lane << 2);
        int4 m4 = *reinterpret_cast<const int4*>(mrow + j0);
        const unsigned bw = sbits[j0 >> 5];
        const int sh = j0 & 31;
        unsigned long long bal[4];
        bal[0] = __ballot((m4.x != 0) & ((bw >> (sh + 0)) & 1u));
        bal[1] = __ballot((m4.y != 0) & ((bw >> (sh + 1)) & 1u));
        bal[2] = __ballot((m4.z != 0) & ((bw >> (sh + 2)) & 1u));
        bal[3] = __ballot((m4.w != 0) & ((bw >> (sh + 3)) & 1u));
        #pragma unroll
        for (int s = 0; s < 4; ++s) {
            unsigned long long b = bal[s];
            while (b) {
                int t = __builtin_ctzll(b);
                b &= b - 1;
                int jj = start + base + (t << 2) + s;
                float4 hv = *reinterpret_cast<const float4*>(
                    h_sub + (size_t)jj * D + (lane << 2));
                acc.x += hv.x; acc.y += hv.y; acc.z += hv.z; acc.w += hv.w;
                cnt++;
            }
        }
    }

    __shared__ float ssum[4][D];
    __shared__ int   scnt[4];
    *reinterpret_cast<float4*>(&ssum[w][lane << 2]) = acc;
    if (lane == 0) scnt[w] = cnt;
    __syncthreads();

    float a = ssum[0][tid] + ssum[1][tid] + ssum[2][tid] + ssum[3][tid];
    psum[(size_t)blockIdx.x * D + tid] = a;
    if (tid == 0) pcnt[blockIdx.x] = scnt[0] + scnt[1] + scnt[2] + scnt[3];
}

// ---------------------------------------------------------------------------
// K2b: combine partials -> mean, cosine, classifier logits
// ---------------------------------------------------------------------------
__global__ __launch_bounds__(256) void seg_combine(
    const float* __restrict__ h_graph,  // [B][D]
    const float* __restrict__ psum,     // [B*NSPLIT][D]
    const int*   __restrict__ pcnt,     // [B*NSPLIT]
    const float* __restrict__ Wc,       // [2D][TT]
    const float* __restrict__ bc,       // [TT]
    float* __restrict__ logits,         // [B][TT]
    float* __restrict__ cos_ws)         // [B]
{
    const int i = blockIdx.x;
    const int tid = threadIdx.x;
    const int lane = tid & 63;
    const int w = tid >> 6;

    float a = 0.f;
    int c = 0;
    #pragma unroll
    for (int p = 0; p < NSPLIT; ++p) {
        a += psum[((size_t)i * NSPLIT + p) * D + tid];
        c += pcnt[i * NSPLIT + p];
    }
    a = (c > 0) ? (a / (float)c) : 0.f;
    const float g = h_graph[(size_t)i * D + tid];

    float r0 = a * a, r1 = g * g, r2 = a * g;
    #pragma unroll
    for (int m = 1; m < 64; m <<= 1) {
        r0 += __shfl_xor(r0, m);
        r1 += __shfl_xor(r1, m);
        r2 += __shfl_xor(r2, m);
    }
    __shared__ float red[4][3];
    if (lane == 0) { red[w][0] = r0; red[w][1] = r1; red[w][2] = r2; }
    __syncthreads();
    if (tid == 0) {
        float a2 = red[0][0] + red[1][0] + red[2][0] + red[3][0];
        float g2 = red[0][1] + red[1][1] + red[2][1] + red[3][1];
        float ag = red[0][2] + red[1][2] + red[2][2] + red[3][2];
        float an = sqrtf(a2), gn = sqrtf(g2);
        float cs = (c > 0) ? (ag / (fmaxf(an, 1e-12f) * fmaxf(gn, 1e-12f))) : 0.f;
        cos_ws[i] = cs;
    }

    float lg[TT];
    #pragma unroll
    for (int t = 0; t < TT; ++t)
        lg[t] = g * Wc[(size_t)tid * TT + t] + a * Wc[(size_t)(D + tid) * TT + t];
    #pragma unroll
    for (int m = 1; m < 64; m <<= 1)
        #pragma unroll
        for (int t = 0; t < TT; ++t) lg[t] += __shfl_xor(lg[t], m);
    __shared__ float lpart[4][TT];
    if (lane == 0)
        #pragma unroll
        for (int t = 0; t < TT; ++t) lpart[w][t] = lg[t];
    __syncthreads();
    if (tid < TT)
        logits[(size_t)i * TT + tid] =
            lpart[0][tid] + lpart[1][tid] + lpart[2][tid] + lpart[3][tid] + bc[tid];
}

// ---------------------------------------------------------------------------
__global__ void loss_kernel(const float* __restrict__ cos_ws,
                            float* __restrict__ out, int B)
{
    const int lane = threadIdx.x;
    float s = 0.f;
    for (int i = lane; i < B; i += 64) s += cos_ws[i];
    #pragma unroll
    for (int m = 1; m < 64; m <<= 1) s += __shfl_xor(s, m);
    if (lane == 0) out[0] = 1.0f - s / (float)B;
}

// ---------------------------------------------------------------------------
extern "C" void kernel_launch(void* const* d_in, const int* in_sizes, int n_in,
                              void* d_out, int out_size, void* d_ws, size_t ws_size,
                              hipStream_t stream)
{
    const float* h_graph = (const float*)d_in[0];
    const float* h_sub   = (const float*)d_in[1];
    const float* W1      = (const float*)d_in[2];
    const float* b1      = (const float*)d_in[3];
    const float* W2      = (const float*)d_in[4];
    const float* b2      = (const float*)d_in[5];
    const float* Wc      = (const float*)d_in[6];
    const float* bc      = (const float*)d_in[7];
    const int*   mask    = (const int*)d_in[8];

    const int B = in_sizes[0] / D;
    const int S = in_sizes[1] / D;

    float* out     = (float*)d_out;
    float* logits  = out;                       // [B*TT]
    float* loss    = out + (size_t)B * TT;      // [1]
    float* submask = loss + 1;                  // [S]

    char* ws = (char*)d_ws;
    short*    W1s    = (short*)ws;                       // 256 KB fp16 frags
    unsigned* gbits  = (unsigned*)(ws + 512 * 1024);     // 8 KB
    int*      pcnt   = (int*)(ws + 528 * 1024);          // 16 KB
    float*    cos_ws = (float*)(ws + 560 * 1024);        // 2 KB
    float*    psum   = (float*)(ws + 1024 * 1024);       // 4 MB

    w1_prep<<<64, 256, 0, stream>>>(W1, W1s);
    gate_mfma<<<S / 64, 256, 0, stream>>>(h_sub, W1s, b1, W2, b2, submask, gbits);
    seg_scan<<<B * NSPLIT, 256, 0, stream>>>(h_sub, mask, gbits, psum, pcnt, S);
    seg_combine<<<B, 256, 0, stream>>>(h_graph, psum, pcnt, Wc, bc, logits, cos_ws);
    loss_kernel<<<1, 64, 0, stream>>>(cos_ws, loss, B);
}

// Round 14
// 80.030 us; speedup vs baseline: 2.5992x; 1.0064x over previous
//
#include <hip/hip_runtime.h>
#include <math.h>

#define D 256
#define H 512
#define TT 10
#define THRESH 0.4f
#define KS 8          // K steps of 32 (D = 256)
#define NSPLIT 8      // scan blocks per graph

typedef __attribute__((ext_vector_type(8))) _Float16 half8;
typedef __attribute__((ext_vector_type(4))) float f32x4;

// ---------------------------------------------------------------------------
// K0: swizzle W1 [D][H] f32 -> fp16 MFMA B-fragments in ws (256 KB).
// layout (half8 = 16B units): idx = (n*8 + k)*64 + lane
//   element i = W1[k*32 + (lane>>4)*8 + i][n*16 + (lane&15)]
// n-tile n = contiguous 8 KB; phase p (16 n-tiles) = contiguous 128 KB.
// ---------------------------------------------------------------------------
__global__ __launch_bounds__(256) void w1_prep(const float* __restrict__ W1,
                                               short* __restrict__ W1s)
{
    const int tid = blockIdx.x * 256 + threadIdx.x;   // 16384 threads
    const int lane = tid & 63;
    const int cell = tid >> 6;                        // 0..255 = (n,k)
    const int k = cell & 7;
    const int n = cell >> 3;
    const int row0 = k * 32 + (lane >> 4) * 8;
    const int col = n * 16 + (lane & 15);
    _Float16 h8[8];
    #pragma unroll
    for (int i = 0; i < 8; ++i)
        h8[i] = (_Float16)W1[(size_t)(row0 + i) * H + col];   // RTN
    *reinterpret_cast<half8*>(W1s + (((size_t)n * 8 + k) * 64 + lane) * 8) =
        *reinterpret_cast<half8*>(h8);
}

// ---------------------------------------------------------------------------
// K1: gate MLP, fp16 1-term MFMA, STATIC-LDS two-phase (no streaming).
// 256 blocks (1/CU), 512 thr = 8 waves x 32 rows = 256 rows/block.
// Phase p: 128 KB of W1-frags (h-cols p*256..p*256+255) resident in LDS;
// phase 0 staged via global_load_lds; phase 1 prefetched to REGISTERS
// during phase-0 compute, ds_written after the phase barrier (T14).
// A (h_sub rows) read ONCE. lp accumulates across phases in-register ->
// fused sigmoid + submask + gbits epilogue. LDS 132 KB -> 1 block/CU,
// 8 waves/CU = 2 waves/SIMD; steady state = pure ds_read + MFMA.
// ---------------------------------------------------------------------------
__global__ __launch_bounds__(512) void gate_mfma(
    const float* __restrict__ h_sub,
    const short* __restrict__ W1s,
    const float* __restrict__ b1,
    const float* __restrict__ W2,
    const float* __restrict__ b2,
    float* __restrict__ submask,
    unsigned* __restrict__ gbits)      // [S/32]
{
    __shared__ __align__(16) short sB[65536];        // 128 KB phase buffer
    __shared__ float sb1[H], sw2[H];                 // 4 KB
    const int tid = threadIdx.x;       // 0..511
    const int lane = tid & 63;
    const int w = tid >> 6;            // wave 0..7
    const int base = blockIdx.x * 256 + w * 32;
    const float bb = b2[0];

    // ---- prologue: stage phase-0 B (128 KB) via global_load_lds ----
    {
        const char* gp = (const char*)W1s + (size_t)tid * 16;
        char* lp0 = (char*)sB + (size_t)tid * 16;
        #pragma unroll
        for (int i = 0; i < 16; ++i) {
            __builtin_amdgcn_global_load_lds(
                (const __attribute__((address_space(1))) void*)(gp + i * 8192),
                (__attribute__((address_space(3))) void*)(lp0 + i * 8192),
                16, 0, 0);
        }
    }
    // biases (512 threads, 512 entries)
    sb1[tid] = b1[tid];
    sw2[tid] = W2[tid];

    // ---- A fragments fp16: 2 s-tiles x 8 k = 64 VGPR, read ONCE ----
    half8 af[2][KS];
    #pragma unroll
    for (int s = 0; s < 2; ++s) {
        const int row = base + s * 16 + (lane & 15);
        const float* rp = h_sub + (size_t)row * D + (lane >> 4) * 8;
        #pragma unroll
        for (int k = 0; k < KS; ++k) {
            float x[8];
            *reinterpret_cast<float4*>(&x[0]) =
                *reinterpret_cast<const float4*>(rp + k * 32);
            *reinterpret_cast<float4*>(&x[4]) =
                *reinterpret_cast<const float4*>(rp + k * 32 + 4);
            _Float16 h8[8];
            #pragma unroll
            for (int i = 0; i < 8; ++i) h8[i] = (_Float16)x[i];
            af[s][k] = *reinterpret_cast<half8*>(h8);
        }
    }

    __syncthreads();   // phase-0 B + biases visible; all vmem drained

    // ---- issue phase-1 B prefetch into registers (lands during phase 0) --
    float4 stg[16];
    {
        const float4* p1 = reinterpret_cast<const float4*>(
                               (const char*)W1s + 131072) + tid;
        #pragma unroll
        for (int i = 0; i < 16; ++i) stg[i] = p1[i * 512];
    }

    float lp[2][4] = {{0.f,0.f,0.f,0.f},{0.f,0.f,0.f,0.f}};

    // ---- phase 0 compute: 16 n-tiles (h-cols 0..255) ----
    #pragma unroll
    for (int nn = 0; nn < 16; ++nn) {
        const int n = (nn + w) & 15;               // wave stagger
        f32x4 acc0 = (f32x4){0.f,0.f,0.f,0.f};
        f32x4 acc1 = (f32x4){0.f,0.f,0.f,0.f};
        #pragma unroll
        for (int k = 0; k < KS; ++k) {
            half8 bh = *reinterpret_cast<const half8*>(
                sB + ((n * 8 + k) * 64 + lane) * 8);
            acc0 = __builtin_amdgcn_mfma_f32_16x16x32_f16(af[0][k], bh, acc0, 0, 0, 0);
            acc1 = __builtin_amdgcn_mfma_f32_16x16x32_f16(af[1][k], bh, acc1, 0, 0, 0);
        }
        const int hc = n * 16 + (lane & 15);
        const float b1h = sb1[hc], w2h = sw2[hc];
        #pragma unroll
        for (int j = 0; j < 4; ++j) {
            float v0 = acc0[j] + b1h;
            v0 = v0 > 0.f ? v0 : 0.f;
            lp[0][j] = fmaf(v0, w2h, lp[0][j]);
            float v1 = acc1[j] + b1h;
            v1 = v1 > 0.f ? v1 : 0.f;
            lp[1][j] = fmaf(v1, w2h, lp[1][j]);
        }
    }

    __syncthreads();   // everyone done READING phase-0 sB

    // ---- write phase-1 B from registers, barrier, compute ----
    {
        float4* dst = reinterpret_cast<float4*>(sB) + tid;
        #pragma unroll
        for (int i = 0; i < 16; ++i) dst[i * 512] = stg[i];
    }
    __syncthreads();

    #pragma unroll
    for (int nn = 0; nn < 16; ++nn) {
        const int n = (nn + w) & 15;
        f32x4 acc0 = (f32x4){0.f,0.f,0.f,0.f};
        f32x4 acc1 = (f32x4){0.f,0.f,0.f,0.f};
        #pragma unroll
        for (int k = 0; k < KS; ++k) {
            half8 bh = *reinterpret_cast<const half8*>(
                sB + ((n * 8 + k) * 64 + lane) * 8);
            acc0 = __builtin_amdgcn_mfma_f32_16x16x32_f16(af[0][k], bh, acc0, 0, 0, 0);
            acc1 = __builtin_amdgcn_mfma_f32_16x16x32_f16(af[1][k], bh, acc1, 0, 0, 0);
        }
        const int hc = 256 + n * 16 + (lane & 15);
        const float b1h = sb1[hc], w2h = sw2[hc];
        #pragma unroll
        for (int j = 0; j < 4; ++j) {
            float v0 = acc0[j] + b1h;
            v0 = v0 > 0.f ? v0 : 0.f;
            lp[0][j] = fmaf(v0, w2h, lp[0][j]);
            float v1 = acc1[j] + b1h;
            v1 = v1 > 0.f ? v1 : 0.f;
            lp[1][j] = fmaf(v1, w2h, lp[1][j]);
        }
    }

    // ---- epilogue: butterfly over 16 h-cols, sigmoid, gbits ----
    #pragma unroll
    for (int m = 1; m < 16; m <<= 1)
        #pragma unroll
        for (int t = 0; t < 2; ++t)
            #pragma unroll
            for (int j = 0; j < 4; ++j)
                lp[t][j] += __shfl_xor(lp[t][j], m);

    const int g = lane >> 4;
    unsigned bits = 0;
    float sig[2][4];
    #pragma unroll
    for (int t = 0; t < 2; ++t)
        #pragma unroll
        for (int j = 0; j < 4; ++j) {
            sig[t][j] = 1.f / (1.f + expf(-(lp[t][j] + bb)));
            if (sig[t][j] > THRESH) bits |= 1u << (t * 16 + g * 4 + j);
        }
    bits |= __shfl_xor(bits, 16);
    bits |= __shfl_xor(bits, 32);
    if (lane == 0) gbits[blockIdx.x * 8 + w] = bits;

    if ((lane & 15) == 0)
        #pragma unroll
        for (int t = 0; t < 2; ++t)
            #pragma unroll
            for (int j = 0; j < 4; ++j)
                submask[base + t * 16 + g * 4 + j] = sig[t][j];
}

// ---------------------------------------------------------------------------
// K2a: mask scan, NSPLIT blocks per graph -> partial sums/counts in ws
// ---------------------------------------------------------------------------
__global__ __launch_bounds__(256) void seg_scan(
    const float* __restrict__ h_sub,    // [S][D]
    const int*   __restrict__ mask,     // [B][S]
    const unsigned* __restrict__ gbits, // [S/32]
    float* __restrict__ psum,           // [B*NSPLIT][D]
    int*   __restrict__ pcnt,           // [B*NSPLIT]
    int S)
{
    const int i = blockIdx.x / NSPLIT;
    const int p = blockIdx.x % NSPLIT;
    const int tid = threadIdx.x;
    const int lane = tid & 63;
    const int w = tid >> 6;
    const int seg = S / NSPLIT;                 // 8192
    const int start = p * seg;
    const int* mrow = mask + (size_t)i * S + start;

    __shared__ unsigned sbits[8192 / 32];       // 256 words = 1 KB
    {
        const int nw = seg / 32;
        for (int t = tid; t < nw; t += 256) sbits[t] = gbits[(start >> 5) + t];
    }
    __syncthreads();

    float4 acc = make_float4(0.f, 0.f, 0.f, 0.f);
    int cnt = 0;

    const int per = seg / 4;                    // per wave: 2048
    for (int base = w * per; base < (w + 1) * per; base += 256) {
        const int j0 = base + (lane << 2);
        int4 m4 = *reinterpret_cast<const int4*>(mrow + j0);
        const unsigned bw = sbits[j0 >> 5];
        const int sh = j0 & 31;
        unsigned long long bal[4];
        bal[0] = __ballot((m4.x != 0) & ((bw >> (sh + 0)) & 1u));
        bal[1] = __ballot((m4.y != 0) & ((bw >> (sh + 1)) & 1u));
        bal[2] = __ballot((m4.z != 0) & ((bw >> (sh + 2)) & 1u));
        bal[3] = __ballot((m4.w != 0) & ((bw >> (sh + 3)) & 1u));
        #pragma unroll
        for (int s = 0; s < 4; ++s) {
            unsigned long long b = bal[s];
            while (b) {
                int t = __builtin_ctzll(b);
                b &= b - 1;
                int jj = start + base + (t << 2) + s;
                float4 hv = *reinterpret_cast<const float4*>(
                    h_sub + (size_t)jj * D + (lane << 2));
                acc.x += hv.x; acc.y += hv.y; acc.z += hv.z; acc.w += hv.w;
                cnt++;
            }
        }
    }

    __shared__ float ssum[4][D];
    __shared__ int   scnt[4];
    *reinterpret_cast<float4*>(&ssum[w][lane << 2]) = acc;
    if (lane == 0) scnt[w] = cnt;
    __syncthreads();

    float a = ssum[0][tid] + ssum[1][tid] + ssum[2][tid] + ssum[3][tid];
    psum[(size_t)blockIdx.x * D + tid] = a;
    if (tid == 0) pcnt[blockIdx.x] = scnt[0] + scnt[1] + scnt[2] + scnt[3];
}

// ---------------------------------------------------------------------------
// K2b: combine partials -> mean, cosine, classifier logits
// ---------------------------------------------------------------------------
__global__ __launch_bounds__(256) void seg_combine(
    const float* __restrict__ h_graph,  // [B][D]
    const float* __restrict__ psum,     // [B*NSPLIT][D]
    const int*   __restrict__ pcnt,     // [B*NSPLIT]
    const float* __restrict__ Wc,       // [2D][TT]
    const float* __restrict__ bc,       // [TT]
    float* __restrict__ logits,         // [B][TT]
    float* __restrict__ cos_ws)         // [B]
{
    const int i = blockIdx.x;
    const int tid = threadIdx.x;
    const int lane = tid & 63;
    const int w = tid >> 6;

    float a = 0.f;
    int c = 0;
    #pragma unroll
    for (int p = 0; p < NSPLIT; ++p) {
        a += psum[((size_t)i * NSPLIT + p) * D + tid];
        c += pcnt[i * NSPLIT + p];
    }
    a = (c > 0) ? (a / (float)c) : 0.f;
    const float g = h_graph[(size_t)i * D + tid];

    float r0 = a * a, r1 = g * g, r2 = a * g;
    #pragma unroll
    for (int m = 1; m < 64; m <<= 1) {
        r0 += __shfl_xor(r0, m);
        r1 += __shfl_xor(r1, m);
        r2 += __shfl_xor(r2, m);
    }
    __shared__ float red[4][3];
    if (lane == 0) { red[w][0] = r0; red[w][1] = r1; red[w][2] = r2; }
    __syncthreads();
    if (tid == 0) {
        float a2 = red[0][0] + red[1][0] + red[2][0] + red[3][0];
        float g2 = red[0][1] + red[1][1] + red[2][1] + red[3][1];
        float ag = red[0][2] + red[1][2] + red[2][2] + red[3][2];
        float an = sqrtf(a2), gn = sqrtf(g2);
        float cs = (c > 0) ? (ag / (fmaxf(an, 1e-12f) * fmaxf(gn, 1e-12f))) : 0.f;
        cos_ws[i] = cs;
    }

    float lg[TT];
    #pragma unroll
    for (int t = 0; t < TT; ++t)
        lg[t] = g * Wc[(size_t)tid * TT + t] + a * Wc[(size_t)(D + tid) * TT + t];
    #pragma unroll
    for (int m = 1; m < 64; m <<= 1)
        #pragma unroll
        for (int t = 0; t < TT; ++t) lg[t] += __shfl_xor(lg[t], m);
    __shared__ float lpart[4][TT];
    if (lane == 0)
        #pragma unroll
        for (int t = 0; t < TT; ++t) lpart[w][t] = lg[t];
    __syncthreads();
    if (tid < TT)
        logits[(size_t)i * TT + tid] =
            lpart[0][tid] + lpart[1][tid] + lpart[2][tid] + lpart[3][tid] + bc[tid];
}

// ---------------------------------------------------------------------------
__global__ void loss_kernel(const float* __restrict__ cos_ws,
                            float* __restrict__ out, int B)
{
    const int lane = threadIdx.x;
    float s = 0.f;
    for (int i = lane; i < B; i += 64) s += cos_ws[i];
    #pragma unroll
    for (int m = 1; m < 64; m <<= 1) s += __shfl_xor(s, m);
    if (lane == 0) out[0] = 1.0f - s / (float)B;
}

// ---------------------------------------------------------------------------
extern "C" void kernel_launch(void* const* d_in, const int* in_sizes, int n_in,
                              void* d_out, int out_size, void* d_ws, size_t ws_size,
                              hipStream_t stream)
{
    const float* h_graph = (const float*)d_in[0];
    const float* h_sub   = (const float*)d_in[1];
    const float* W1      = (const float*)d_in[2];
    const float* b1      = (const float*)d_in[3];
    const float* W2      = (const float*)d_in[4];
    const float* b2      = (const float*)d_in[5];
    const float* Wc      = (const float*)d_in[6];
    const float* bc      = (const float*)d_in[7];
    const int*   mask    = (const int*)d_in[8];

    const int B = in_sizes[0] / D;
    const int S = in_sizes[1] / D;

    float* out     = (float*)d_out;
    float* logits  = out;                       // [B*TT]
    float* loss    = out + (size_t)B * TT;      // [1]
    float* submask = loss + 1;                  // [S]

    char* ws = (char*)d_ws;
    short*    W1s    = (short*)ws;                       // 256 KB fp16 frags
    unsigned* gbits  = (unsigned*)(ws + 512 * 1024);     // 8 KB
    int*      pcnt   = (int*)(ws + 528 * 1024);          // 16 KB
    float*    cos_ws = (float*)(ws + 560 * 1024);        // 2 KB
    float*    psum   = (float*)(ws + 1024 * 1024);       // 4 MB

    w1_prep<<<64, 256, 0, stream>>>(W1, W1s);
    gate_mfma<<<S / 256, 512, 0, stream>>>(h_sub, W1s, b1, W2, b2, submask, gbits);
    seg_scan<<<B * NSPLIT, 256, 0, stream>>>(h_sub, mask, gbits, psum, pcnt, S);
    seg_combine<<<B, 256, 0, stream>>>(h_graph, psum, pcnt, Wc, bc, logits, cos_ws);
    loss_kernel<<<1, 64, 0, stream>>>(cos_ws, loss, B);
}

// Round 15
// 76.124 us; speedup vs baseline: 2.7326x; 1.0513x over previous
//
#include <hip/hip_runtime.h>
#include <math.h>

#define D 256
#define H 512
#define TT 10
#define THRESH 0.4f
#define KS 8          // K steps of 32 (D = 256)
#define NSPLIT 8      // scan blocks per graph

typedef __attribute__((ext_vector_type(8))) _Float16 half8;
typedef __attribute__((ext_vector_type(4))) float f32x4;

// ---------------------------------------------------------------------------
// K0: swizzle W1 [D][H] f32 -> fp16 MFMA B-fragments in ws (256 KB).
// layout (half8 = 16B units): idx = (n*8 + k)*64 + lane
//   element i = W1[k*32 + (lane>>4)*8 + i][n*16 + (lane&15)]
// n-tile n = contiguous 8 KB; phase p (16 n-tiles) = contiguous 128 KB.
// ---------------------------------------------------------------------------
__global__ __launch_bounds__(256) void w1_prep(const float* __restrict__ W1,
                                               short* __restrict__ W1s)
{
    const int tid = blockIdx.x * 256 + threadIdx.x;   // 16384 threads
    const int lane = tid & 63;
    const int cell = tid >> 6;                        // 0..255 = (n,k)
    const int k = cell & 7;
    const int n = cell >> 3;
    const int row0 = k * 32 + (lane >> 4) * 8;
    const int col = n * 16 + (lane & 15);
    _Float16 h8[8];
    #pragma unroll
    for (int i = 0; i < 8; ++i)
        h8[i] = (_Float16)W1[(size_t)(row0 + i) * H + col];   // RTN
    *reinterpret_cast<half8*>(W1s + (((size_t)n * 8 + k) * 64 + lane) * 8) =
        *reinterpret_cast<half8*>(h8);
}

// ---------------------------------------------------------------------------
// K1: gate MLP, fp16 1-term MFMA, static-LDS two-phase, 4 S-TILES/WAVE.
// 256 blocks (1/CU), 256 thr = 4 waves x 64 rows = 256 rows/block.
// Arithmetic intensity doubled vs 2-s-tile: each 1 KB B ds_read feeds
// 4 MFMAs -> per-CU LDS traffic 1 MB (~5 us), 4 independent MFMA chains.
// Both phases staged via global_load_lds (128 KB each); steady state is
// pure ds_read + MFMA. A (h_sub) read ONCE in prologue (overlaps stage).
// LDS 132 KB -> 1 block/CU; VGPR ~200 (af 128 + acc 16 + lp 16 + misc).
// ---------------------------------------------------------------------------
__global__ __launch_bounds__(256, 1) void gate_mfma(
    const float* __restrict__ h_sub,
    const short* __restrict__ W1s,
    const float* __restrict__ b1,
    const float* __restrict__ W2,
    const float* __restrict__ b2,
    float* __restrict__ submask,
    unsigned* __restrict__ gbits)      // [S/32]
{
    __shared__ __align__(16) short sB[65536];        // 128 KB phase buffer
    __shared__ float sb1[H], sw2[H];                 // 4 KB
    const int tid = threadIdx.x;       // 0..255
    const int lane = tid & 63;
    const int w = tid >> 6;            // wave 0..3
    const int base = blockIdx.x * 256 + w * 64;      // this wave's 64 rows
    const float bb = b2[0];

    // stage phase p's 128 KB of B-frags: 256 thr x 16 B x 32 iters
    auto stagePhase = [&](int p) {
        const char* gp = (const char*)W1s + (size_t)p * 131072 + (size_t)tid * 16;
        char* lp0 = (char*)sB + (size_t)tid * 16;
        #pragma unroll
        for (int i = 0; i < 32; ++i) {
            __builtin_amdgcn_global_load_lds(
                (const __attribute__((address_space(1))) void*)(gp + i * 4096),
                (__attribute__((address_space(3))) void*)(lp0 + i * 4096),
                16, 0, 0);
        }
    };

    stagePhase(0);                     // async; lands before first barrier
    sb1[tid] = b1[tid];       sb1[tid + 256] = b1[tid + 256];
    sw2[tid] = W2[tid];       sw2[tid + 256] = W2[tid + 256];

    // ---- A fragments fp16: 4 s-tiles x 8 k = 128 VGPR, read ONCE ----
    half8 af[4][KS];
    #pragma unroll
    for (int s = 0; s < 4; ++s) {
        const int row = base + s * 16 + (lane & 15);
        const float* rp = h_sub + (size_t)row * D + (lane >> 4) * 8;
        #pragma unroll
        for (int k = 0; k < KS; ++k) {
            float x[8];
            *reinterpret_cast<float4*>(&x[0]) =
                *reinterpret_cast<const float4*>(rp + k * 32);
            *reinterpret_cast<float4*>(&x[4]) =
                *reinterpret_cast<const float4*>(rp + k * 32 + 4);
            _Float16 h8[8];
            #pragma unroll
            for (int i = 0; i < 8; ++i) h8[i] = (_Float16)x[i];
            af[s][k] = *reinterpret_cast<half8*>(h8);
        }
    }

    float lp[4][4];
    #pragma unroll
    for (int s = 0; s < 4; ++s)
        #pragma unroll
        for (int j = 0; j < 4; ++j) lp[s][j] = 0.f;

    #pragma unroll
    for (int p = 0; p < 2; ++p) {
        __syncthreads();   // phase-p B + (p=0: biases) visible; vmem drained

        #pragma unroll
        for (int nn = 0; nn < 16; ++nn) {
            const int n = (nn + w * 4) & 15;         // wave stagger
            f32x4 acc[4];
            #pragma unroll
            for (int s = 0; s < 4; ++s) acc[s] = (f32x4){0.f,0.f,0.f,0.f};

            __builtin_amdgcn_s_setprio(1);
            #pragma unroll
            for (int k = 0; k < KS; ++k) {
                half8 bh = *reinterpret_cast<const half8*>(
                    sB + ((n * 8 + k) * 64 + lane) * 8);
                acc[0] = __builtin_amdgcn_mfma_f32_16x16x32_f16(af[0][k], bh, acc[0], 0, 0, 0);
                acc[1] = __builtin_amdgcn_mfma_f32_16x16x32_f16(af[1][k], bh, acc[1], 0, 0, 0);
                acc[2] = __builtin_amdgcn_mfma_f32_16x16x32_f16(af[2][k], bh, acc[2], 0, 0, 0);
                acc[3] = __builtin_amdgcn_mfma_f32_16x16x32_f16(af[3][k], bh, acc[3], 0, 0, 0);
            }
            __builtin_amdgcn_s_setprio(0);

            const int hc = p * 256 + n * 16 + (lane & 15);
            const float b1h = sb1[hc], w2h = sw2[hc];
            #pragma unroll
            for (int s = 0; s < 4; ++s)
                #pragma unroll
                for (int j = 0; j < 4; ++j) {
                    float v = acc[s][j] + b1h;
                    v = v > 0.f ? v : 0.f;
                    lp[s][j] = fmaf(v, w2h, lp[s][j]);
                }
        }

        if (p == 0) {
            __syncthreads();           // all waves done READING phase-0 sB
            stagePhase(1);             // restage; next barrier drains vmcnt
        }
    }

    // ---- epilogue: butterfly over 16 h-cols, sigmoid, gbits ----
    #pragma unroll
    for (int m = 1; m < 16; m <<= 1)
        #pragma unroll
        for (int s = 0; s < 4; ++s)
            #pragma unroll
            for (int j = 0; j < 4; ++j)
                lp[s][j] += __shfl_xor(lp[s][j], m);

    const int g = lane >> 4;
    unsigned b0 = 0, b1w = 0;
    float sig[4][4];
    #pragma unroll
    for (int s = 0; s < 4; ++s)
        #pragma unroll
        for (int j = 0; j < 4; ++j) {
            sig[s][j] = 1.f / (1.f + expf(-(lp[s][j] + bb)));
            const int r = s * 16 + g * 4 + j;        // row within 64
            if (sig[s][j] > THRESH) {
                if (r < 32) b0 |= 1u << r;
                else        b1w |= 1u << (r - 32);
            }
        }
    b0  |= __shfl_xor(b0, 16);  b0  |= __shfl_xor(b0, 32);
    b1w |= __shfl_xor(b1w, 16); b1w |= __shfl_xor(b1w, 32);
    if (lane == 0) {
        gbits[blockIdx.x * 8 + w * 2 + 0] = b0;
        gbits[blockIdx.x * 8 + w * 2 + 1] = b1w;
    }
    if ((lane & 15) == 0)
        #pragma unroll
        for (int s = 0; s < 4; ++s)
            #pragma unroll
            for (int j = 0; j < 4; ++j)
                submask[base + s * 16 + g * 4 + j] = sig[s][j];
}

// ---------------------------------------------------------------------------
// K2a: mask scan, NSPLIT blocks per graph -> partial sums/counts in ws
// ---------------------------------------------------------------------------
__global__ __launch_bounds__(256) void seg_scan(
    const float* __restrict__ h_sub,    // [S][D]
    const int*   __restrict__ mask,     // [B][S]
    const unsigned* __restrict__ gbits, // [S/32]
    float* __restrict__ psum,           // [B*NSPLIT][D]
    int*   __restrict__ pcnt,           // [B*NSPLIT]
    int S)
{
    const int i = blockIdx.x / NSPLIT;
    const int p = blockIdx.x % NSPLIT;
    const int tid = threadIdx.x;
    const int lane = tid & 63;
    const int w = tid >> 6;
    const int seg = S / NSPLIT;                 // 8192
    const int start = p * seg;
    const int* mrow = mask + (size_t)i * S + start;

    __shared__ unsigned sbits[8192 / 32];       // 256 words = 1 KB
    {
        const int nw = seg / 32;
        for (int t = tid; t < nw; t += 256) sbits[t] = gbits[(start >> 5) + t];
    }
    __syncthreads();

    float4 acc = make_float4(0.f, 0.f, 0.f, 0.f);
    int cnt = 0;

    const int per = seg / 4;                    // per wave: 2048
    for (int base = w * per; base < (w + 1) * per; base += 256) {
        const int j0 = base + (lane << 2);
        int4 m4 = *reinterpret_cast<const int4*>(mrow + j0);
        const unsigned bw = sbits[j0 >> 5];
        const int sh = j0 & 31;
        unsigned long long bal[4];
        bal[0] = __ballot((m4.x != 0) & ((bw >> (sh + 0)) & 1u));
        bal[1] = __ballot((m4.y != 0) & ((bw >> (sh + 1)) & 1u));
        bal[2] = __ballot((m4.z != 0) & ((bw >> (sh + 2)) & 1u));
        bal[3] = __ballot((m4.w != 0) & ((bw >> (sh + 3)) & 1u));
        #pragma unroll
        for (int s = 0; s < 4; ++s) {
            unsigned long long b = bal[s];
            while (b) {
                int t = __builtin_ctzll(b);
                b &= b - 1;
                int jj = start + base + (t << 2) + s;
                float4 hv = *reinterpret_cast<const float4*>(
                    h_sub + (size_t)jj * D + (lane << 2));
                acc.x += hv.x; acc.y += hv.y; acc.z += hv.z; acc.w += hv.w;
                cnt++;
            }
        }
    }

    __shared__ float ssum[4][D];
    __shared__ int   scnt[4];
    *reinterpret_cast<float4*>(&ssum[w][lane << 2]) = acc;
    if (lane == 0) scnt[w] = cnt;
    __syncthreads();

    float a = ssum[0][tid] + ssum[1][tid] + ssum[2][tid] + ssum[3][tid];
    psum[(size_t)blockIdx.x * D + tid] = a;
    if (tid == 0) pcnt[blockIdx.x] = scnt[0] + scnt[1] + scnt[2] + scnt[3];
}

// ---------------------------------------------------------------------------
// K2b: combine partials -> mean, cosine, classifier logits
// ---------------------------------------------------------------------------
__global__ __launch_bounds__(256) void seg_combine(
    const float* __restrict__ h_graph,  // [B][D]
    const float* __restrict__ psum,     // [B*NSPLIT][D]
    const int*   __restrict__ pcnt,     // [B*NSPLIT]
    const float* __restrict__ Wc,       // [2D][TT]
    const float* __restrict__ bc,       // [TT]
    float* __restrict__ logits,         // [B][TT]
    float* __restrict__ cos_ws)         // [B]
{
    const int i = blockIdx.x;
    const int tid = threadIdx.x;
    const int lane = tid & 63;
    const int w = tid >> 6;

    float a = 0.f;
    int c = 0;
    #pragma unroll
    for (int p = 0; p < NSPLIT; ++p) {
        a += psum[((size_t)i * NSPLIT + p) * D + tid];
        c += pcnt[i * NSPLIT + p];
    }
    a = (c > 0) ? (a / (float)c) : 0.f;
    const float g = h_graph[(size_t)i * D + tid];

    float r0 = a * a, r1 = g * g, r2 = a * g;
    #pragma unroll
    for (int m = 1; m < 64; m <<= 1) {
        r0 += __shfl_xor(r0, m);
        r1 += __shfl_xor(r1, m);
        r2 += __shfl_xor(r2, m);
    }
    __shared__ float red[4][3];
    if (lane == 0) { red[w][0] = r0; red[w][1] = r1; red[w][2] = r2; }
    __syncthreads();
    if (tid == 0) {
        float a2 = red[0][0] + red[1][0] + red[2][0] + red[3][0];
        float g2 = red[0][1] + red[1][1] + red[2][1] + red[3][1];
        float ag = red[0][2] + red[1][2] + red[2][2] + red[3][2];
        float an = sqrtf(a2), gn = sqrtf(g2);
        float cs = (c > 0) ? (ag / (fmaxf(an, 1e-12f) * fmaxf(gn, 1e-12f))) : 0.f;
        cos_ws[i] = cs;
    }

    float lg[TT];
    #pragma unroll
    for (int t = 0; t < TT; ++t)
        lg[t] = g * Wc[(size_t)tid * TT + t] + a * Wc[(size_t)(D + tid) * TT + t];
    #pragma unroll
    for (int m = 1; m < 64; m <<= 1)
        #pragma unroll
        for (int t = 0; t < TT; ++t) lg[t] += __shfl_xor(lg[t], m);
    __shared__ float lpart[4][TT];
    if (lane == 0)
        #pragma unroll
        for (int t = 0; t < TT; ++t) lpart[w][t] = lg[t];
    __syncthreads();
    if (tid < TT)
        logits[(size_t)i * TT + tid] =
            lpart[0][tid] + lpart[1][tid] + lpart[2][tid] + lpart[3][tid] + bc[tid];
}

// ---------------------------------------------------------------------------
__global__ void loss_kernel(const float* __restrict__ cos_ws,
                            float* __restrict__ out, int B)
{
    const int lane = threadIdx.x;
    float s = 0.f;
    for (int i = lane; i < B; i += 64) s += cos_ws[i];
    #pragma unroll
    for (int m = 1; m < 64; m <<= 1) s += __shfl_xor(s, m);
    if (lane == 0) out[0] = 1.0f - s / (float)B;
}

// ---------------------------------------------------------------------------
extern "C" void kernel_launch(void* const* d_in, const int* in_sizes, int n_in,
                              void* d_out, int out_size, void* d_ws, size_t ws_size,
                              hipStream_t stream)
{
    const float* h_graph = (const float*)d_in[0];
    const float* h_sub   = (const float*)d_in[1];
    const float* W1      = (const float*)d_in[2];
    const float* b1      = (const float*)d_in[3];
    const float* W2      = (const float*)d_in[4];
    const float* b2      = (const float*)d_in[5];
    const float* Wc      = (const float*)d_in[6];
    const float* bc      = (const float*)d_in[7];
    const int*   mask    = (const int*)d_in[8];

    const int B = in_sizes[0] / D;
    const int S = in_sizes[1] / D;

    float* out     = (float*)d_out;
    float* logits  = out;                       // [B*TT]
    float* loss    = out + (size_t)B * TT;      // [1]
    float* submask = loss + 1;                  // [S]

    char* ws = (char*)d_ws;
    short*    W1s    = (short*)ws;                       // 256 KB fp16 frags
    unsigned* gbits  = (unsigned*)(ws + 512 * 1024);     // 8 KB
    int*      pcnt   = (int*)(ws + 528 * 1024);          // 16 KB
    float*    cos_ws = (float*)(ws + 560 * 1024);        // 2 KB
    float*    psum   = (float*)(ws + 1024 * 1024);       // 4 MB

    w1_prep<<<64, 256, 0, stream>>>(W1, W1s);
    gate_mfma<<<S / 256, 256, 0, stream>>>(h_sub, W1s, b1, W2, b2, submask, gbits);
    seg_scan<<<B * NSPLIT, 256, 0, stream>>>(h_sub, mask, gbits, psum, pcnt, S);
    seg_combine<<<B, 256, 0, stream>>>(h_graph, psum, pcnt, Wc, bc, logits, cos_ws);
    loss_kernel<<<1, 64, 0, stream>>>(cos_ws, loss, B);
}